// Round 6
// baseline (454.034 us; speedup 1.0000x reference)
//
#include <hip/hip_runtime.h>
#include <math.h>

// ---------------------------------------------------------------------------
// GAT 2-layer pipeline for MI355X.
// N=50000 nodes, E=850000 edges (incl self loops), feat 256, H=4 x 64 -> 256.
//
//   convert_w / convert_x8: fp32 -> (hi,lo) bf16 split (split-bf16 GEMM).
//   CSR build: zero, hist, two-level scan, scatter, sort_csr (canonical order).
//   gemm_mfma: C = A @ W^T, A pre-split bf16 hi/lo -> pure-copy staging
//     (r6: removes ~128 VALU conv ops/thread/K-step that made it VALU-bound).
//   scompute: wave-per-node, ushort4-vectorized.
//   aggregate4: wave-per-node fused softmax-stats + gather-aggregate.
//     Determinism: scatter's atomicAdd permutes segments per call; sort_csr
//     canonicalizes ascending-src (deg<=64), deg>64 path is order-invariant
//     min-sweep -> output bits identical every call (post-timing tripwire).
//     r4 lesson: do NOT widen per-edge footprint (8-lane/32-feat regressed).
//     r6: layer-1 epilogue writes hi/lo bf16 directly into d_out scratch
//     (identical numerics to the old in-gemm split of the same fp32 value).
// ---------------------------------------------------------------------------

typedef __attribute__((ext_vector_type(8))) short short8;          // 8 x bf16
typedef __attribute__((ext_vector_type(4))) float f32x4;           // MFMA acc
typedef _Float16 half8 __attribute__((ext_vector_type(8)));        // 8 x fp16

__device__ inline short f2bf(float f) {
    unsigned u = __float_as_uint(f);
    unsigned r = (u + 0x7FFF + ((u >> 16) & 1)) >> 16;  // RN-even
    return (short)r;
}
__device__ inline float bf2f(short b) {
    return __uint_as_float(((unsigned)(unsigned short)b) << 16);
}
__device__ inline unsigned short f2h(float f) {
    _Float16 h = (_Float16)f;
    unsigned short u;
    __builtin_memcpy(&u, &h, 2);
    return u;
}
__device__ inline float h2f(unsigned short u) {
    _Float16 h;
    __builtin_memcpy(&h, &u, 2);
    return (float)h;
}

__global__ void convert_w(const float* __restrict__ W, short* __restrict__ Whi,
                          short* __restrict__ Wlo, int n) {
    int i = blockIdx.x * 256 + threadIdx.x;
    if (i < n) {
        float v = W[i];
        short h = f2bf(v);
        Whi[i] = h;
        Wlo[i] = f2bf(v - bf2f(h));
    }
}

// vectorized fp32 -> (hi,lo) bf16 split, 8 elems/thread
__global__ void convert_x8(const float* __restrict__ X, short* __restrict__ Xhi,
                           short* __restrict__ Xlo, long n) {
    long i = ((long)blockIdx.x * 256 + threadIdx.x) * 8;
    if (i + 8 <= n) {
        float4 v0 = *(const float4*)&X[i];
        float4 v1 = *(const float4*)&X[i + 4];
        float av[8] = {v0.x, v0.y, v0.z, v0.w, v1.x, v1.y, v1.z, v1.w};
        short8 hi, lo;
        #pragma unroll
        for (int j = 0; j < 8; ++j) {
            short h = f2bf(av[j]);
            hi[j] = h;
            lo[j] = f2bf(av[j] - bf2f(h));
        }
        *(short8*)&Xhi[i] = hi;
        *(short8*)&Xlo[i] = lo;
    } else {
        for (long k = i; k < n; ++k) {
            float v = X[k];
            short h = f2bf(v);
            Xhi[k] = h;
            Xlo[k] = f2bf(v - bf2f(h));
        }
    }
}

// C[M x 256] (FP16) = A @ B^T, A and B both pre-split bf16 hi/lo.
// 128x128 tile, BK=32, 4 waves; each wave owns a 32x128 strip (2 m-frags
// x 8 n-frags, 3-pass split-bf16 MFMA). Pad-40 LDS rows: b128 reads are
// 2-way bank aliased = free. Staging is pure short8 copies (no VALU conv).
__global__ __launch_bounds__(256) void gemm_mfma(const short* __restrict__ Ah_g,
                                                 const short* __restrict__ Al_g,
                                                 const short* __restrict__ Bh_g,
                                                 const short* __restrict__ Bl_g,
                                                 unsigned short* __restrict__ C, int M) {
    __shared__ short Ah[128 * 40];
    __shared__ short Al[128 * 40];
    __shared__ short Bh[128 * 40];
    __shared__ short Bl[128 * 40];
    const int tid = threadIdx.x;
    const int m0 = blockIdx.x * 128;
    const int n0 = blockIdx.y * 128;
    const int w = tid >> 6, lane = tid & 63;
    const int l15 = lane & 15, q = lane >> 4;

    f32x4 acc[2][8];
    #pragma unroll
    for (int mt = 0; mt < 2; ++mt)
        #pragma unroll
        for (int nt = 0; nt < 8; ++nt) acc[mt][nt] = (f32x4){0.f, 0.f, 0.f, 0.f};

    const int ar = tid >> 1;          // 0..127 (row within tile)
    const int ak = (tid & 1) * 16;    // 0 or 16 (k-offset, 16 elems)

    for (int k0 = 0; k0 < 256; k0 += 32) {
        int gm = m0 + ar;
        if (gm < M) {
            const short* a0 = &Ah_g[(size_t)gm * 256 + k0 + ak];
            *(short8*)&Ah[ar * 40 + ak]     = *(const short8*)a0;
            *(short8*)&Ah[ar * 40 + ak + 8] = *(const short8*)(a0 + 8);
            const short* a1 = &Al_g[(size_t)gm * 256 + k0 + ak];
            *(short8*)&Al[ar * 40 + ak]     = *(const short8*)a1;
            *(short8*)&Al[ar * 40 + ak + 8] = *(const short8*)(a1 + 8);
        } else {
            short8 z = (short8){0, 0, 0, 0, 0, 0, 0, 0};
            *(short8*)&Ah[ar * 40 + ak]     = z;
            *(short8*)&Ah[ar * 40 + ak + 8] = z;
            *(short8*)&Al[ar * 40 + ak]     = z;
            *(short8*)&Al[ar * 40 + ak + 8] = z;
        }
        {
            const short* s0 = &Bh_g[(size_t)(n0 + ar) * 256 + k0 + ak];
            *(short8*)&Bh[ar * 40 + ak]     = *(const short8*)s0;
            *(short8*)&Bh[ar * 40 + ak + 8] = *(const short8*)(s0 + 8);
            const short* s1 = &Bl_g[(size_t)(n0 + ar) * 256 + k0 + ak];
            *(short8*)&Bl[ar * 40 + ak]     = *(const short8*)s1;
            *(short8*)&Bl[ar * 40 + ak + 8] = *(const short8*)(s1 + 8);
        }
        __syncthreads();
        short8 ahi[2], alo[2];
        #pragma unroll
        for (int mt = 0; mt < 2; ++mt) {
            int rowA = w * 32 + mt * 16 + l15;
            ahi[mt] = *(short8*)&Ah[rowA * 40 + q * 8];
            alo[mt] = *(short8*)&Al[rowA * 40 + q * 8];
        }
        #pragma unroll
        for (int nt = 0; nt < 8; ++nt) {
            int rowB = nt * 16 + l15;
            short8 bhi = *(short8*)&Bh[rowB * 40 + q * 8];
            short8 blo = *(short8*)&Bl[rowB * 40 + q * 8];
            #pragma unroll
            for (int mt = 0; mt < 2; ++mt) {
                acc[mt][nt] = __builtin_amdgcn_mfma_f32_16x16x32_bf16(ahi[mt], bhi, acc[mt][nt], 0, 0, 0);
                acc[mt][nt] = __builtin_amdgcn_mfma_f32_16x16x32_bf16(alo[mt], bhi, acc[mt][nt], 0, 0, 0);
                acc[mt][nt] = __builtin_amdgcn_mfma_f32_16x16x32_bf16(ahi[mt], blo, acc[mt][nt], 0, 0, 0);
            }
        }
        __syncthreads();
    }
    #pragma unroll
    for (int mt = 0; mt < 2; ++mt) {
        #pragma unroll
        for (int nt = 0; nt < 8; ++nt) {
            #pragma unroll
            for (int r = 0; r < 4; ++r) {
                int gm = m0 + w * 32 + mt * 16 + q * 4 + r;
                if (gm < M) C[(size_t)gm * 256 + n0 + nt * 16 + l15] = f2h(acc[mt][nt][r]);
            }
        }
    }
}

// -------------------- CSR build --------------------
__global__ void zero_int(int* __restrict__ p, int n) {
    int i = blockIdx.x * 256 + threadIdx.x;
    if (i < n) p[i] = 0;
}

__global__ void hist_kernel(const int* __restrict__ dst, int* __restrict__ deg, int E) {
    int i = blockIdx.x * 256 + threadIdx.x;
    if (i < E) atomicAdd(&deg[dst[i]], 1);
}

__global__ __launch_bounds__(1024) void scan1(const int* __restrict__ deg,
                                              int* __restrict__ lex,
                                              int* __restrict__ bsums, int n) {
    __shared__ int sh[1024];
    int tid = threadIdx.x;
    int i = blockIdx.x * 1024 + tid;
    int v = (i < n) ? deg[i] : 0;
    sh[tid] = v;
    __syncthreads();
    #pragma unroll
    for (int off = 1; off < 1024; off <<= 1) {
        int t2 = (tid >= off) ? sh[tid - off] : 0;
        __syncthreads();
        sh[tid] += t2;
        __syncthreads();
    }
    if (i < n) lex[i] = sh[tid] - v;
    if (tid == 1023) bsums[blockIdx.x] = sh[1023];
}

__global__ __launch_bounds__(1024) void scan2(const int* __restrict__ bsums,
                                              int* __restrict__ boffs,
                                              int* __restrict__ offs, int nb, int n) {
    __shared__ int sh[1024];
    int tid = threadIdx.x;
    int v = (tid < nb) ? bsums[tid] : 0;
    sh[tid] = v;
    __syncthreads();
    #pragma unroll
    for (int off = 1; off < 1024; off <<= 1) {
        int t2 = (tid >= off) ? sh[tid - off] : 0;
        __syncthreads();
        sh[tid] += t2;
        __syncthreads();
    }
    if (tid < nb) boffs[tid] = sh[tid] - v;
    if (tid == nb - 1) offs[n] = sh[tid];
}

__global__ __launch_bounds__(1024) void scan3(int* __restrict__ offs,
                                              int* __restrict__ cur,
                                              const int* __restrict__ boffs, int n) {
    int i = blockIdx.x * 1024 + threadIdx.x;
    if (i < n) {
        int o = offs[i] + boffs[blockIdx.x];
        offs[i] = o;
        cur[i] = o;
    }
}

__global__ void scatter_kernel(const int* __restrict__ src, const int* __restrict__ dst,
                               int* __restrict__ cur, int* __restrict__ sorted, int E) {
    int i = blockIdx.x * 256 + threadIdx.x;
    if (i < E) {
        int p = atomicAdd(&cur[dst[i]], 1);
        sorted[p] = src[i];
    }
}

// Canonicalize each CSR segment (deg<=64) with a 64-lane bitonic sort.
// deg>64 segments are left as-is (aggregate4's big path is order-invariant).
// No barriers -> per-wave early return is safe.
__global__ __launch_bounds__(256) void sort_csr(const int* __restrict__ offs,
                                                int* __restrict__ sorted, int N) {
    const int w = threadIdx.x >> 6, lane = threadIdx.x & 63;
    const int node = blockIdx.x * 4 + w;
    if (node >= N) return;
    const int b = offs[node], e = offs[node + 1];
    const int deg = e - b;
    if (deg < 2 || deg > 64) return;
    int key = (lane < deg) ? sorted[b + lane] : 0x7FFFFFFF;
    #pragma unroll
    for (int k = 2; k <= 64; k <<= 1) {
        #pragma unroll
        for (int j = k >> 1; j > 0; j >>= 1) {
            int other = __shfl_xor(key, j, 64);
            bool keepMin = ((lane & j) == 0) == ((lane & k) == 0);
            int mn = min(key, other), mh = max(key, other);
            key = keepMin ? mn : mh;
        }
    }
    if (lane < deg) sorted[b + lane] = key;
}

// -------------------- attention scalars (fp16 hp in) --------------------
// Wave per node, 4 nodes/block. Lane covers 4 contiguous features (8B
// ushort4 load). Fixed-order butterflies -> deterministic.
template <int NH>
__global__ __launch_bounds__(256) void scompute(const unsigned short* __restrict__ hp,
                                                const float* __restrict__ a_src,
                                                const float* __restrict__ a_dst,
                                                float* __restrict__ s_src,
                                                float* __restrict__ s_dst, int N) {
    const int w = threadIdx.x >> 6, lane = threadIdx.x & 63;
    const int node = blockIdx.x * 4 + w;
    if (node >= N) return;          // no barriers below — safe
    const int f0 = lane * 4;
    ushort4 uv = *(const ushort4*)(hp + (size_t)node * 256 + f0);
    float4 as = *(const float4*)(a_src + f0);
    float4 ad = *(const float4*)(a_dst + f0);
    float x0 = h2f(uv.x), x1 = h2f(uv.y), x2 = h2f(uv.z), x3 = h2f(uv.w);
    float p1 = x0 * as.x + x1 * as.y + x2 * as.z + x3 * as.w;
    float p2 = x0 * ad.x + x1 * ad.y + x2 * ad.z + x3 * ad.w;
    if constexpr (NH == 4) {
        #pragma unroll
        for (int off = 1; off < 16; off <<= 1) {
            p1 += __shfl_xor(p1, off, 64);
            p2 += __shfl_xor(p2, off, 64);
        }
        if ((lane & 15) == 0) {
            s_src[node * 4 + (lane >> 4)] = p1;
            s_dst[node * 4 + (lane >> 4)] = p2;
        }
    } else {
        #pragma unroll
        for (int off = 1; off < 64; off <<= 1) {
            p1 += __shfl_xor(p1, off, 64);
            p2 += __shfl_xor(p2, off, 64);
        }
        if (lane == 0) {
            s_src[node] = p1;
            s_dst[node] = p2;
        }
    }
}

// -------------------- fused stats + aggregation (bitwise-deterministic) ----
// One wave per node, 4 nodes per block. CSR segments are pre-sorted
// (sort_csr) so order is canonical. Stats phase computes pv per edge,
// stores (src, pv[]) to LDS. One barrier. Gather: 4 edges/iter, 16 lanes
// x 16 features per edge, with one-ahead (s,p) prefetch.
// SPLIT=true: write output as (hi,lo) bf16 split (for next-layer GEMM).
template <int NH, bool RELU, bool SPLIT>
__global__ __launch_bounds__(256) void aggregate4(const unsigned short* __restrict__ hp,
                                                  const float* __restrict__ ssrc,
                                                  const float* __restrict__ sdst,
                                                  const int* __restrict__ offs,
                                                  const int* __restrict__ sorted,
                                                  float* __restrict__ out,
                                                  short* __restrict__ ohi,
                                                  short* __restrict__ olo, int N) {
    __shared__ int   s_sh[4][64];
    __shared__ float p_sh[4][64][NH];

    const int w = threadIdx.x >> 6, lane = threadIdx.x & 63;
    const int node_raw = blockIdx.x * 4 + w;
    const bool node_ok = node_raw < N;
    const int node = node_ok ? node_raw : (N - 1);   // clamp; no early return
    constexpr int NF = 256 / NH;

    const int b = offs[node], e = offs[node + 1];
    const int deg = e - b;

    float sv[NH];
    #pragma unroll
    for (int h = 0; h < NH; ++h) sv[h] = sdst[node * NH + h];

    float lv[NH], mx[NH];
    const bool small = (deg <= 64);

    if (small) {
        const bool valid = lane < deg;
        const int mys = valid ? sorted[b + lane] : 0;   // pre-sorted ascending

        // ---- stats on sorted sequence ----
        float evv[NH];
        if constexpr (NH == 4) {
            float4 sa = *(const float4*)&ssrc[(size_t)mys * 4];
            evv[0] = sa.x + sv[0]; evv[1] = sa.y + sv[1];
            evv[2] = sa.z + sv[2]; evv[3] = sa.w + sv[3];
        } else {
            evv[0] = ssrc[mys] + sv[0];
        }
        #pragma unroll
        for (int h = 0; h < NH; ++h) {
            float ev = evv[h];
            ev = ev > 0.f ? ev : 0.2f * ev;
            evv[h] = valid ? ev : -INFINITY;
            mx[h] = evv[h];
        }
        #pragma unroll
        for (int off = 32; off > 0; off >>= 1)
            #pragma unroll
            for (int h = 0; h < NH; ++h)
                mx[h] = fmaxf(mx[h], __shfl_xor(mx[h], off, 64));

        float pv[NH];
        #pragma unroll
        for (int h = 0; h < NH; ++h) {
            pv[h] = valid ? __expf(evv[h] - mx[h]) : 0.f;
            lv[h] = pv[h];
        }
        #pragma unroll
        for (int off = 32; off > 0; off >>= 1)
            #pragma unroll
            for (int h = 0; h < NH; ++h)
                lv[h] += __shfl_xor(lv[h], off, 64);

        // stash sorted (src, pv[]) for the gather phase
        s_sh[w][lane] = mys;
        #pragma unroll
        for (int h = 0; h < NH; ++h) p_sh[w][lane][h] = pv[h];
    } else {
        // ---- deg > 64 (never populated for this graph; kept correct) ----
        #pragma unroll
        for (int h = 0; h < NH; ++h) mx[h] = -INFINITY;
        for (int c = b + lane; c < e; c += 64) {
            int s = sorted[c];
            #pragma unroll
            for (int h = 0; h < NH; ++h) {
                float ev = ssrc[s * NH + h] + sv[h];
                ev = ev > 0.f ? ev : 0.2f * ev;
                mx[h] = fmaxf(mx[h], ev);   // max is order-invariant
            }
        }
        #pragma unroll
        for (int off = 32; off > 0; off >>= 1)
            #pragma unroll
            for (int h = 0; h < NH; ++h)
                mx[h] = fmaxf(mx[h], __shfl_xor(mx[h], off, 64));
    }

    __syncthreads();   // all waves reach this exactly once

    if (small) {
        // ---- gather: 4 edges/iter; 16 lanes x 16 features per edge ----
        const int quarter = lane >> 4;
        const int l16 = lane & 15;
        const int f0 = l16 * 16;
        const int head = f0 / NF;        // NH=4: l16/4; NH=1: 0

        float acc[16];
        #pragma unroll
        for (int k = 0; k < 16; ++k) acc[k] = 0.f;

        const int iters = (deg + 3) >> 2;
        // one-ahead (s,p) prefetch: LDS reads for iter t+1 issue during t's FMAs
        int j = quarter;
        bool jv = j < deg;
        int jj = jv ? j : 0;
        int s = s_sh[w][jj];
        float p = jv ? p_sh[w][jj][head] : 0.f;
        for (int t2 = 0; t2 < iters; ++t2) {
            const unsigned short* row = hp + (size_t)s * 256 + f0;
            half8 v0 = *(const half8*)(row);
            half8 v1 = *(const half8*)(row + 8);
            float pc = p;
            int jn = 4 * (t2 + 1) + quarter;
            bool jvn = jn < deg;
            int jjn = jvn ? jn : 0;
            s = s_sh[w][jjn];
            p = jvn ? p_sh[w][jjn][head] : 0.f;
            #pragma unroll
            for (int k = 0; k < 8; ++k) {
                acc[k]     = fmaf(pc, (float)v0[k], acc[k]);
                acc[8 + k] = fmaf(pc, (float)v1[k], acc[8 + k]);
            }
        }
        // reduce across the 4 edge-quarters (wave-uniform, all lanes active)
        #pragma unroll
        for (int k = 0; k < 16; ++k) {
            acc[k] += __shfl_xor(acc[k], 16, 64);
            acc[k] += __shfl_xor(acc[k], 32, 64);
        }
        if (node_ok && lane < 16) {
            float li = 1.0f / (lv[head] + 1e-16f);
            float o[16];
            #pragma unroll
            for (int k = 0; k < 16; ++k) {
                o[k] = acc[k] * li;
                if (RELU) o[k] = fmaxf(o[k], 0.f);
            }
            if constexpr (SPLIT) {
                short8 h0, h1, l0, l1;
                #pragma unroll
                for (int k = 0; k < 8; ++k) {
                    short hh = f2bf(o[k]);
                    h0[k] = hh; l0[k] = f2bf(o[k] - bf2f(hh));
                    short hh2 = f2bf(o[8 + k]);
                    h1[k] = hh2; l1[k] = f2bf(o[8 + k] - bf2f(hh2));
                }
                *(short8*)&ohi[(size_t)node * 256 + f0]     = h0;
                *(short8*)&ohi[(size_t)node * 256 + f0 + 8] = h1;
                *(short8*)&olo[(size_t)node * 256 + f0]     = l0;
                *(short8*)&olo[(size_t)node * 256 + f0 + 8] = l1;
            } else {
                float* op = &out[(size_t)node * 256 + f0];
                *(float4*)&op[0]  = make_float4(o[0], o[1], o[2], o[3]);
                *(float4*)&op[4]  = make_float4(o[4], o[5], o[6], o[7]);
                *(float4*)&op[8]  = make_float4(o[8], o[9], o[10], o[11]);
                *(float4*)&op[12] = make_float4(o[12], o[13], o[14], o[15]);
            }
        }
    } else {
        // ---- deg > 64 deterministic ascending-src sweep (rare path) ----
        const int half = lane >> 5;
        const int l32 = lane & 31;
        const int f0 = l32 * 8;
        const int head = f0 / NF;

        float acc[8];
        #pragma unroll
        for (int k = 0; k < 8; ++k) acc[k] = 0.f;
        #pragma unroll
        for (int h = 0; h < NH; ++h) lv[h] = 0.f;

        int last = -1, round = 0;
        for (;;) {
            int myMin = 0x7FFFFFFF, myCnt = 0;
            for (int c = b + lane; c < e; c += 64) {
                int s = sorted[c];
                if (s > last) {
                    if (s < myMin) { myMin = s; myCnt = 1; }
                    else if (s == myMin) ++myCnt;
                }
            }
            #pragma unroll
            for (int off = 32; off > 0; off >>= 1) {
                int om = __shfl_xor(myMin, off, 64);
                int oc = __shfl_xor(myCnt, off, 64);
                if (om < myMin) { myMin = om; myCnt = oc; }
                else if (om == myMin) myCnt += oc;
            }
            if (myMin == 0x7FFFFFFF) break;     // wave-uniform exit
            const bool mine = ((round & 1) == half);
            float cf = (float)myCnt;
            float ph[NH];
            #pragma unroll
            for (int h = 0; h < NH; ++h) {
                float ev = ssrc[myMin * NH + h] + sv[h];
                ev = ev > 0.f ? ev : 0.2f * ev;
                ph[h] = __expf(ev - mx[h]);
            }
            if (mine && l32 == 0) {             // one lane per half owns lv
                #pragma unroll
                for (int h = 0; h < NH; ++h) lv[h] += cf * ph[h];
            }
            if (mine) {
                float p = cf * ph[head];
                half8 v = *(const half8*)(hp + (size_t)myMin * 256 + f0);
                #pragma unroll
                for (int k = 0; k < 8; ++k) acc[k] = fmaf(p, (float)v[k], acc[k]);
            }
            last = myMin; ++round;
        }
        #pragma unroll
        for (int off = 32; off > 0; off >>= 1)
            #pragma unroll
            for (int h = 0; h < NH; ++h)
                lv[h] += __shfl_xor(lv[h], off, 64);

        #pragma unroll
        for (int k = 0; k < 8; ++k) acc[k] += __shfl_xor(acc[k], 32, 64);

        if (node_ok && lane < 32) {
            float li = 1.0f / (lv[head] + 1e-16f);
            float o[8];
            #pragma unroll
            for (int k = 0; k < 8; ++k) {
                o[k] = acc[k] * li;
                if (RELU) o[k] = fmaxf(o[k], 0.f);
            }
            if constexpr (SPLIT) {
                short8 h0, l0;
                #pragma unroll
                for (int k = 0; k < 8; ++k) {
                    short hh = f2bf(o[k]);
                    h0[k] = hh; l0[k] = f2bf(o[k] - bf2f(hh));
                }
                *(short8*)&ohi[(size_t)node * 256 + f0] = h0;
                *(short8*)&olo[(size_t)node * 256 + f0] = l0;
            } else {
                *(float4*)&out[(size_t)node * 256 + f0]     = make_float4(o[0], o[1], o[2], o[3]);
                *(float4*)&out[(size_t)node * 256 + f0 + 4] = make_float4(o[4], o[5], o[6], o[7]);
            }
        }
    }
}

// ---------------------------------------------------------------------------
extern "C" void kernel_launch(void* const* d_in, const int* in_sizes, int n_in,
                              void* d_out, int out_size, void* d_ws, size_t ws_size,
                              hipStream_t stream) {
    const float* x   = (const float*)d_in[0];
    const int*   ei  = (const int*)d_in[1];
    const float* W1  = (const float*)d_in[2];
    const float* a1s = (const float*)d_in[3];
    const float* a1d = (const float*)d_in[4];
    const float* W2  = (const float*)d_in[5];
    const float* a2s = (const float*)d_in[6];
    const float* a2d = (const float*)d_in[7];
    float* out = (float*)d_out;

    const int N = in_sizes[0] / 256;
    const int E = in_sizes[1] / 2;
    const int* src = ei;
    const int* dst = ei + E;

    // workspace carve-up
    unsigned short* hp = (unsigned short*)d_ws;     // N*256 fp16
    float* ssrc  = (float*)(hp + (size_t)N * 256);  // N*4
    float* sdst  = ssrc + (size_t)N * 4;            // N*4
    int*   deg   = (int*)(sdst + (size_t)N * 4);    // N
    int*   cur   = deg + N;                         // N
    int*   offs  = cur + N;                         // N+1
    int*   sorted= offs + N + 1;                    // E
    int*   bsums = sorted + E;                      // 64
    int*   boffs = bsums + 64;                      // 64
    short* w1hi  = (short*)(boffs + 64);            // 65536
    short* w1lo  = w1hi + 65536;
    short* w2hi  = w1lo + 65536;
    short* w2lo  = w2hi + 65536;

    // d_out doubles as bf16 hi/lo scratch for the GEMM A-operand:
    // N*256 fp32 bytes == 2 * (N*256 bf16). x's converted copy is dead by
    // the time layer-1 aggregate overwrites it; final aggregate writes fp32.
    short* xhi = (short*)d_out;
    short* xlo = xhi + (size_t)N * 256;

    const int nb = (N + 1023) / 1024;

    // ---- weight + input split ----
    convert_w<<<256, 256, 0, stream>>>(W1, w1hi, w1lo, 65536);
    convert_w<<<256, 256, 0, stream>>>(W2, w2hi, w2lo, 65536);
    long nx = (long)N * 256;
    convert_x8<<<(int)((nx / 8 + 255) / 256), 256, 0, stream>>>(x, xhi, xlo, nx);

    // ---- CSR build ----
    zero_int<<<(N + 255) / 256, 256, 0, stream>>>(deg, N);
    hist_kernel<<<(E + 255) / 256, 256, 0, stream>>>(dst, deg, E);
    scan1<<<nb, 1024, 0, stream>>>(deg, offs, bsums, N);
    scan2<<<1, 1024, 0, stream>>>(bsums, boffs, offs, nb, N);
    scan3<<<nb, 1024, 0, stream>>>(offs, cur, boffs, N);
    scatter_kernel<<<(E + 255) / 256, 256, 0, stream>>>(src, dst, cur, sorted, E);

    dim3 gg((N + 127) / 128, 2);
    int aggblocks = (N + 3) / 4;
    sort_csr<<<aggblocks, 256, 0, stream>>>(offs, sorted, N);

    // ---- layer 1 ----
    gemm_mfma<<<gg, 256, 0, stream>>>(xhi, xlo, w1hi, w1lo, hp, N);
    scompute<4><<<aggblocks, 256, 0, stream>>>(hp, a1s, a1d, ssrc, sdst, N);
    aggregate4<4, true, true><<<aggblocks, 256, 0, stream>>>(hp, ssrc, sdst, offs, sorted,
                                                             nullptr, xhi, xlo, N);

    // ---- layer 2 ----
    gemm_mfma<<<gg, 256, 0, stream>>>(xhi, xlo, w2hi, w2lo, hp, N);
    scompute<1><<<aggblocks, 256, 0, stream>>>(hp, a2s, a2d, ssrc, sdst, N);
    aggregate4<1, false, false><<<aggblocks, 256, 0, stream>>>(hp, ssrc, sdst, offs, sorted,
                                                               out, nullptr, nullptr, N);
}

// Round 7
// 414.622 us; speedup vs baseline: 1.0951x; 1.0951x over previous
//
#include <hip/hip_runtime.h>
#include <math.h>

// ---------------------------------------------------------------------------
// GAT 2-layer pipeline for MI355X.
// N=50000 nodes, E=850000 edges (incl self loops), feat 256, H=4 x 64 -> 256.
//
//   convert_h8: fp32 -> fp16 (vectorized). convert_w_h: W -> fp16.
//   CSR build: zero, hist, two-level scan, scatter, sort_csr (canonical).
//   gemm_mfma: C[fp16] = A[fp16] @ B[fp16]^T single-pass 16x16x32_f16 MFMA.
//     r7: replaced 3-pass split-bf16 (48 MFMA + 20 ds_read/wave-K-step) with
//     single-pass f16 (16 MFMA + 10 ds_read). Error analysis: f16 input
//     rounding adds ~8e-4 abs, an order below the existing fp16-storage-of-hp
//     error (2^-8 = current absmax); threshold 1.38e-2.
//   scompute: wave-per-node, ushort4-vectorized.
//   aggregate4: wave-per-node fused softmax-stats + gather-aggregate.
//     Determinism: scatter's atomicAdd permutes segments per call; sort_csr
//     canonicalizes ascending-src -> bitwise-identical output every call.
//     r4 lesson: do NOT widen per-edge footprint (regressed).
//     r6 lesson: one-ahead (s,p) prefetch REGRESSED (75.5->81us) — removed;
//     plain r5 gather loop restored.
//     F16OUT=true (layer 1): epilogue writes h as fp16 for next GEMM.
// ---------------------------------------------------------------------------

typedef __attribute__((ext_vector_type(8))) short short8;
typedef __attribute__((ext_vector_type(8))) unsigned short ushort8;
typedef __attribute__((ext_vector_type(4))) float f32x4;           // MFMA acc
typedef _Float16 half8 __attribute__((ext_vector_type(8)));        // 8 x fp16

__device__ inline unsigned short f2h(float f) {
    _Float16 h = (_Float16)f;
    unsigned short u;
    __builtin_memcpy(&u, &h, 2);
    return u;
}
__device__ inline float h2f(unsigned short u) {
    _Float16 h;
    __builtin_memcpy(&h, &u, 2);
    return (float)h;
}

// fp32 -> fp16, 8 elems/thread
__global__ void convert_h8(const float* __restrict__ X, unsigned short* __restrict__ Xh,
                           long n) {
    long i = ((long)blockIdx.x * 256 + threadIdx.x) * 8;
    if (i + 8 <= n) {
        float4 v0 = *(const float4*)&X[i];
        float4 v1 = *(const float4*)&X[i + 4];
        ushort8 o;
        o[0] = f2h(v0.x); o[1] = f2h(v0.y); o[2] = f2h(v0.z); o[3] = f2h(v0.w);
        o[4] = f2h(v1.x); o[5] = f2h(v1.y); o[6] = f2h(v1.z); o[7] = f2h(v1.w);
        *(ushort8*)&Xh[i] = o;
    } else {
        for (long k = i; k < n; ++k) Xh[k] = f2h(X[k]);
    }
}

// C[M x 256] (fp16) = A[M x 256] (fp16) @ B^T (fp16), single-pass f16 MFMA.
// 128x128 tile, BK=32, 4 waves; each wave: 2 m-frags x 8 n-frags.
// Pad-40 LDS rows: b128 reads are 2-way bank aliased = free.
__global__ __launch_bounds__(256) void gemm_mfma(const unsigned short* __restrict__ A_g,
                                                 const unsigned short* __restrict__ B_g,
                                                 unsigned short* __restrict__ C, int M) {
    __shared__ unsigned short Ah[128 * 40];
    __shared__ unsigned short Bh[128 * 40];
    const int tid = threadIdx.x;
    const int m0 = blockIdx.x * 128;
    const int n0 = blockIdx.y * 128;
    const int w = tid >> 6, lane = tid & 63;
    const int l15 = lane & 15, q = lane >> 4;

    f32x4 acc[2][8];
    #pragma unroll
    for (int mt = 0; mt < 2; ++mt)
        #pragma unroll
        for (int nt = 0; nt < 8; ++nt) acc[mt][nt] = (f32x4){0.f, 0.f, 0.f, 0.f};

    const int ar = tid >> 1;          // 0..127 (row within tile)
    const int ak = (tid & 1) * 16;    // 0 or 16 (k-offset, 16 elems)

    for (int k0 = 0; k0 < 256; k0 += 32) {
        int gm = m0 + ar;
        if (gm < M) {
            const unsigned short* a0 = &A_g[(size_t)gm * 256 + k0 + ak];
            *(ushort8*)&Ah[ar * 40 + ak]     = *(const ushort8*)a0;
            *(ushort8*)&Ah[ar * 40 + ak + 8] = *(const ushort8*)(a0 + 8);
        } else {
            ushort8 z = (ushort8){0, 0, 0, 0, 0, 0, 0, 0};
            *(ushort8*)&Ah[ar * 40 + ak]     = z;
            *(ushort8*)&Ah[ar * 40 + ak + 8] = z;
        }
        {
            const unsigned short* b0 = &B_g[(size_t)(n0 + ar) * 256 + k0 + ak];
            *(ushort8*)&Bh[ar * 40 + ak]     = *(const ushort8*)b0;
            *(ushort8*)&Bh[ar * 40 + ak + 8] = *(const ushort8*)(b0 + 8);
        }
        __syncthreads();
        half8 a[2];
        #pragma unroll
        for (int mt = 0; mt < 2; ++mt) {
            int rowA = w * 32 + mt * 16 + l15;
            a[mt] = *(half8*)&Ah[rowA * 40 + q * 8];
        }
        #pragma unroll
        for (int nt = 0; nt < 8; ++nt) {
            int rowB = nt * 16 + l15;
            half8 bf = *(half8*)&Bh[rowB * 40 + q * 8];
            #pragma unroll
            for (int mt = 0; mt < 2; ++mt)
                acc[mt][nt] = __builtin_amdgcn_mfma_f32_16x16x32_f16(a[mt], bf, acc[mt][nt], 0, 0, 0);
        }
        __syncthreads();
    }
    #pragma unroll
    for (int mt = 0; mt < 2; ++mt) {
        #pragma unroll
        for (int nt = 0; nt < 8; ++nt) {
            #pragma unroll
            for (int r = 0; r < 4; ++r) {
                int gm = m0 + w * 32 + mt * 16 + q * 4 + r;
                if (gm < M) C[(size_t)gm * 256 + n0 + nt * 16 + l15] = f2h(acc[mt][nt][r]);
            }
        }
    }
}

// -------------------- CSR build --------------------
__global__ void zero_int(int* __restrict__ p, int n) {
    int i = blockIdx.x * 256 + threadIdx.x;
    if (i < n) p[i] = 0;
}

__global__ void hist_kernel(const int* __restrict__ dst, int* __restrict__ deg, int E) {
    int i = blockIdx.x * 256 + threadIdx.x;
    if (i < E) atomicAdd(&deg[dst[i]], 1);
}

__global__ __launch_bounds__(1024) void scan1(const int* __restrict__ deg,
                                              int* __restrict__ lex,
                                              int* __restrict__ bsums, int n) {
    __shared__ int sh[1024];
    int tid = threadIdx.x;
    int i = blockIdx.x * 1024 + tid;
    int v = (i < n) ? deg[i] : 0;
    sh[tid] = v;
    __syncthreads();
    #pragma unroll
    for (int off = 1; off < 1024; off <<= 1) {
        int t2 = (tid >= off) ? sh[tid - off] : 0;
        __syncthreads();
        sh[tid] += t2;
        __syncthreads();
    }
    if (i < n) lex[i] = sh[tid] - v;
    if (tid == 1023) bsums[blockIdx.x] = sh[1023];
}

__global__ __launch_bounds__(1024) void scan2(const int* __restrict__ bsums,
                                              int* __restrict__ boffs,
                                              int* __restrict__ offs, int nb, int n) {
    __shared__ int sh[1024];
    int tid = threadIdx.x;
    int v = (tid < nb) ? bsums[tid] : 0;
    sh[tid] = v;
    __syncthreads();
    #pragma unroll
    for (int off = 1; off < 1024; off <<= 1) {
        int t2 = (tid >= off) ? sh[tid - off] : 0;
        __syncthreads();
        sh[tid] += t2;
        __syncthreads();
    }
    if (tid < nb) boffs[tid] = sh[tid] - v;
    if (tid == nb - 1) offs[n] = sh[tid];
}

__global__ __launch_bounds__(1024) void scan3(int* __restrict__ offs,
                                              int* __restrict__ cur,
                                              const int* __restrict__ boffs, int n) {
    int i = blockIdx.x * 1024 + threadIdx.x;
    if (i < n) {
        int o = offs[i] + boffs[blockIdx.x];
        offs[i] = o;
        cur[i] = o;
    }
}

__global__ void scatter_kernel(const int* __restrict__ src, const int* __restrict__ dst,
                               int* __restrict__ cur, int* __restrict__ sorted, int E) {
    int i = blockIdx.x * 256 + threadIdx.x;
    if (i < E) {
        int p = atomicAdd(&cur[dst[i]], 1);
        sorted[p] = src[i];
    }
}

// Canonicalize each CSR segment (deg<=64) with a 64-lane bitonic sort.
// deg>64 segments are left as-is (aggregate4's big path is order-invariant).
// No barriers -> per-wave early return is safe.
__global__ __launch_bounds__(256) void sort_csr(const int* __restrict__ offs,
                                                int* __restrict__ sorted, int N) {
    const int w = threadIdx.x >> 6, lane = threadIdx.x & 63;
    const int node = blockIdx.x * 4 + w;
    if (node >= N) return;
    const int b = offs[node], e = offs[node + 1];
    const int deg = e - b;
    if (deg < 2 || deg > 64) return;
    int key = (lane < deg) ? sorted[b + lane] : 0x7FFFFFFF;
    #pragma unroll
    for (int k = 2; k <= 64; k <<= 1) {
        #pragma unroll
        for (int j = k >> 1; j > 0; j >>= 1) {
            int other = __shfl_xor(key, j, 64);
            bool keepMin = ((lane & j) == 0) == ((lane & k) == 0);
            int mn = min(key, other), mh = max(key, other);
            key = keepMin ? mn : mh;
        }
    }
    if (lane < deg) sorted[b + lane] = key;
}

// -------------------- attention scalars (fp16 hp in) --------------------
// Wave per node, 4 nodes/block. Lane covers 4 contiguous features (8B
// ushort4 load). Fixed-order butterflies -> deterministic.
template <int NH>
__global__ __launch_bounds__(256) void scompute(const unsigned short* __restrict__ hp,
                                                const float* __restrict__ a_src,
                                                const float* __restrict__ a_dst,
                                                float* __restrict__ s_src,
                                                float* __restrict__ s_dst, int N) {
    const int w = threadIdx.x >> 6, lane = threadIdx.x & 63;
    const int node = blockIdx.x * 4 + w;
    if (node >= N) return;          // no barriers below — safe
    const int f0 = lane * 4;
    ushort4 uv = *(const ushort4*)(hp + (size_t)node * 256 + f0);
    float4 as = *(const float4*)(a_src + f0);
    float4 ad = *(const float4*)(a_dst + f0);
    float x0 = h2f(uv.x), x1 = h2f(uv.y), x2 = h2f(uv.z), x3 = h2f(uv.w);
    float p1 = x0 * as.x + x1 * as.y + x2 * as.z + x3 * as.w;
    float p2 = x0 * ad.x + x1 * ad.y + x2 * ad.z + x3 * ad.w;
    if constexpr (NH == 4) {
        #pragma unroll
        for (int off = 1; off < 16; off <<= 1) {
            p1 += __shfl_xor(p1, off, 64);
            p2 += __shfl_xor(p2, off, 64);
        }
        if ((lane & 15) == 0) {
            s_src[node * 4 + (lane >> 4)] = p1;
            s_dst[node * 4 + (lane >> 4)] = p2;
        }
    } else {
        #pragma unroll
        for (int off = 1; off < 64; off <<= 1) {
            p1 += __shfl_xor(p1, off, 64);
            p2 += __shfl_xor(p2, off, 64);
        }
        if (lane == 0) {
            s_src[node] = p1;
            s_dst[node] = p2;
        }
    }
}

// -------------------- fused stats + aggregation (bitwise-deterministic) ----
// One wave per node, 4 nodes per block. CSR segments are pre-sorted
// (sort_csr) so order is canonical. Stats phase computes pv per edge,
// stores (src, pv[]) to LDS. One barrier. Gather: 4 edges/iter, 16 lanes
// x 16 features per edge (r5 loop — no prefetch, r6 lesson).
// F16OUT=true: write output as fp16 (A-operand of the next GEMM).
template <int NH, bool RELU, bool F16OUT>
__global__ __launch_bounds__(256) void aggregate4(const unsigned short* __restrict__ hp,
                                                  const float* __restrict__ ssrc,
                                                  const float* __restrict__ sdst,
                                                  const int* __restrict__ offs,
                                                  const int* __restrict__ sorted,
                                                  float* __restrict__ out,
                                                  unsigned short* __restrict__ outh, int N) {
    __shared__ int   s_sh[4][64];
    __shared__ float p_sh[4][64][NH];

    const int w = threadIdx.x >> 6, lane = threadIdx.x & 63;
    const int node_raw = blockIdx.x * 4 + w;
    const bool node_ok = node_raw < N;
    const int node = node_ok ? node_raw : (N - 1);   // clamp; no early return
    constexpr int NF = 256 / NH;

    const int b = offs[node], e = offs[node + 1];
    const int deg = e - b;

    float sv[NH];
    #pragma unroll
    for (int h = 0; h < NH; ++h) sv[h] = sdst[node * NH + h];

    float lv[NH], mx[NH];
    const bool small = (deg <= 64);

    if (small) {
        const bool valid = lane < deg;
        const int mys = valid ? sorted[b + lane] : 0;   // pre-sorted ascending

        // ---- stats on sorted sequence ----
        float evv[NH];
        if constexpr (NH == 4) {
            float4 sa = *(const float4*)&ssrc[(size_t)mys * 4];
            evv[0] = sa.x + sv[0]; evv[1] = sa.y + sv[1];
            evv[2] = sa.z + sv[2]; evv[3] = sa.w + sv[3];
        } else {
            evv[0] = ssrc[mys] + sv[0];
        }
        #pragma unroll
        for (int h = 0; h < NH; ++h) {
            float ev = evv[h];
            ev = ev > 0.f ? ev : 0.2f * ev;
            evv[h] = valid ? ev : -INFINITY;
            mx[h] = evv[h];
        }
        #pragma unroll
        for (int off = 32; off > 0; off >>= 1)
            #pragma unroll
            for (int h = 0; h < NH; ++h)
                mx[h] = fmaxf(mx[h], __shfl_xor(mx[h], off, 64));

        float pv[NH];
        #pragma unroll
        for (int h = 0; h < NH; ++h) {
            pv[h] = valid ? __expf(evv[h] - mx[h]) : 0.f;
            lv[h] = pv[h];
        }
        #pragma unroll
        for (int off = 32; off > 0; off >>= 1)
            #pragma unroll
            for (int h = 0; h < NH; ++h)
                lv[h] += __shfl_xor(lv[h], off, 64);

        // stash sorted (src, pv[]) for the gather phase
        s_sh[w][lane] = mys;
        #pragma unroll
        for (int h = 0; h < NH; ++h) p_sh[w][lane][h] = pv[h];
    } else {
        // ---- deg > 64 (never populated for this graph; kept correct) ----
        #pragma unroll
        for (int h = 0; h < NH; ++h) mx[h] = -INFINITY;
        for (int c = b + lane; c < e; c += 64) {
            int s = sorted[c];
            #pragma unroll
            for (int h = 0; h < NH; ++h) {
                float ev = ssrc[s * NH + h] + sv[h];
                ev = ev > 0.f ? ev : 0.2f * ev;
                mx[h] = fmaxf(mx[h], ev);   // max is order-invariant
            }
        }
        #pragma unroll
        for (int off = 32; off > 0; off >>= 1)
            #pragma unroll
            for (int h = 0; h < NH; ++h)
                mx[h] = fmaxf(mx[h], __shfl_xor(mx[h], off, 64));
    }

    __syncthreads();   // all waves reach this exactly once

    if (small) {
        // ---- gather: 4 edges/iter; 16 lanes x 16 features per edge ----
        const int quarter = lane >> 4;
        const int l16 = lane & 15;
        const int f0 = l16 * 16;
        const int head = f0 / NF;        // NH=4: l16/4; NH=1: 0

        float acc[16];
        #pragma unroll
        for (int k = 0; k < 16; ++k) acc[k] = 0.f;

        const int iters = (deg + 3) >> 2;
        for (int t2 = 0; t2 < iters; ++t2) {
            int j = 4 * t2 + quarter;
            bool jv = j < deg;
            int jj = jv ? j : 0;
            int s = s_sh[w][jj];
            float p = jv ? p_sh[w][jj][head] : 0.f;
            const unsigned short* row = hp + (size_t)s * 256 + f0;
            half8 v0 = *(const half8*)(row);
            half8 v1 = *(const half8*)(row + 8);
            #pragma unroll
            for (int k = 0; k < 8; ++k) {
                acc[k]     = fmaf(p, (float)v0[k], acc[k]);
                acc[8 + k] = fmaf(p, (float)v1[k], acc[8 + k]);
            }
        }
        // reduce across the 4 edge-quarters (wave-uniform, all lanes active)
        #pragma unroll
        for (int k = 0; k < 16; ++k) {
            acc[k] += __shfl_xor(acc[k], 16, 64);
            acc[k] += __shfl_xor(acc[k], 32, 64);
        }
        if (node_ok && lane < 16) {
            float li = 1.0f / (lv[head] + 1e-16f);
            float o[16];
            #pragma unroll
            for (int k = 0; k < 16; ++k) {
                o[k] = acc[k] * li;
                if (RELU) o[k] = fmaxf(o[k], 0.f);
            }
            if constexpr (F16OUT) {
                ushort8 u0, u1;
                #pragma unroll
                for (int k = 0; k < 8; ++k) {
                    u0[k] = f2h(o[k]);
                    u1[k] = f2h(o[8 + k]);
                }
                *(ushort8*)&outh[(size_t)node * 256 + f0]     = u0;
                *(ushort8*)&outh[(size_t)node * 256 + f0 + 8] = u1;
            } else {
                float* op = &out[(size_t)node * 256 + f0];
                *(float4*)&op[0]  = make_float4(o[0], o[1], o[2], o[3]);
                *(float4*)&op[4]  = make_float4(o[4], o[5], o[6], o[7]);
                *(float4*)&op[8]  = make_float4(o[8], o[9], o[10], o[11]);
                *(float4*)&op[12] = make_float4(o[12], o[13], o[14], o[15]);
            }
        }
    } else {
        // ---- deg > 64 deterministic ascending-src sweep (rare path) ----
        const int half = lane >> 5;
        const int l32 = lane & 31;
        const int f0 = l32 * 8;
        const int head = f0 / NF;

        float acc[8];
        #pragma unroll
        for (int k = 0; k < 8; ++k) acc[k] = 0.f;
        #pragma unroll
        for (int h = 0; h < NH; ++h) lv[h] = 0.f;

        int last = -1, round = 0;
        for (;;) {
            int myMin = 0x7FFFFFFF, myCnt = 0;
            for (int c = b + lane; c < e; c += 64) {
                int s = sorted[c];
                if (s > last) {
                    if (s < myMin) { myMin = s; myCnt = 1; }
                    else if (s == myMin) ++myCnt;
                }
            }
            #pragma unroll
            for (int off = 32; off > 0; off >>= 1) {
                int om = __shfl_xor(myMin, off, 64);
                int oc = __shfl_xor(myCnt, off, 64);
                if (om < myMin) { myMin = om; myCnt = oc; }
                else if (om == myMin) myCnt += oc;
            }
            if (myMin == 0x7FFFFFFF) break;     // wave-uniform exit
            const bool mine = ((round & 1) == half);
            float cf = (float)myCnt;
            float ph[NH];
            #pragma unroll
            for (int h = 0; h < NH; ++h) {
                float ev = ssrc[myMin * NH + h] + sv[h];
                ev = ev > 0.f ? ev : 0.2f * ev;
                ph[h] = __expf(ev - mx[h]);
            }
            if (mine && l32 == 0) {             // one lane per half owns lv
                #pragma unroll
                for (int h = 0; h < NH; ++h) lv[h] += cf * ph[h];
            }
            if (mine) {
                float p = cf * ph[head];
                half8 v = *(const half8*)(hp + (size_t)myMin * 256 + f0);
                #pragma unroll
                for (int k = 0; k < 8; ++k) acc[k] = fmaf(p, (float)v[k], acc[k]);
            }
            last = myMin; ++round;
        }
        #pragma unroll
        for (int off = 32; off > 0; off >>= 1)
            #pragma unroll
            for (int h = 0; h < NH; ++h)
                lv[h] += __shfl_xor(lv[h], off, 64);

        #pragma unroll
        for (int k = 0; k < 8; ++k) acc[k] += __shfl_xor(acc[k], 32, 64);

        if (node_ok && lane < 32) {
            float li = 1.0f / (lv[head] + 1e-16f);
            float o[8];
            #pragma unroll
            for (int k = 0; k < 8; ++k) {
                o[k] = acc[k] * li;
                if (RELU) o[k] = fmaxf(o[k], 0.f);
            }
            if constexpr (F16OUT) {
                ushort8 u0;
                #pragma unroll
                for (int k = 0; k < 8; ++k) u0[k] = f2h(o[k]);
                *(ushort8*)&outh[(size_t)node * 256 + f0] = u0;
            } else {
                *(float4*)&out[(size_t)node * 256 + f0]     = make_float4(o[0], o[1], o[2], o[3]);
                *(float4*)&out[(size_t)node * 256 + f0 + 4] = make_float4(o[4], o[5], o[6], o[7]);
            }
        }
    }
}

// ---------------------------------------------------------------------------
extern "C" void kernel_launch(void* const* d_in, const int* in_sizes, int n_in,
                              void* d_out, int out_size, void* d_ws, size_t ws_size,
                              hipStream_t stream) {
    const float* x   = (const float*)d_in[0];
    const int*   ei  = (const int*)d_in[1];
    const float* W1  = (const float*)d_in[2];
    const float* a1s = (const float*)d_in[3];
    const float* a1d = (const float*)d_in[4];
    const float* W2  = (const float*)d_in[5];
    const float* a2s = (const float*)d_in[6];
    const float* a2d = (const float*)d_in[7];
    float* out = (float*)d_out;

    const int N = in_sizes[0] / 256;
    const int E = in_sizes[1] / 2;
    const int* src = ei;
    const int* dst = ei + E;

    // workspace carve-up
    unsigned short* hp = (unsigned short*)d_ws;     // N*256 fp16
    float* ssrc  = (float*)(hp + (size_t)N * 256);  // N*4
    float* sdst  = ssrc + (size_t)N * 4;            // N*4
    int*   deg   = (int*)(sdst + (size_t)N * 4);    // N
    int*   cur   = deg + N;                         // N
    int*   offs  = cur + N;                         // N+1
    int*   sorted= offs + N + 1;                    // E
    int*   bsums = sorted + E;                      // 64
    int*   boffs = bsums + 64;                      // 64
    unsigned short* w1h = (unsigned short*)(boffs + 64);  // 65536 fp16
    unsigned short* w2h = w1h + 65536;                    // 65536 fp16

    // d_out doubles as fp16 scratch: xh (layer-1 A) in the first half,
    // hh (layer-1 output = layer-2 A) in the second half. Both dead before
    // the final aggregate overwrites d_out with fp32 output.
    unsigned short* xh = (unsigned short*)d_out;    // N*256 fp16
    unsigned short* hh = xh + (size_t)N * 256;      // N*256 fp16

    const int nb = (N + 1023) / 1024;

    // ---- weight + input fp16 conversion ----
    convert_h8<<<32, 256, 0, stream>>>(W1, w1h, 65536);
    convert_h8<<<32, 256, 0, stream>>>(W2, w2h, 65536);
    long nx = (long)N * 256;
    convert_h8<<<(int)((nx / 8 + 255) / 256), 256, 0, stream>>>(x, xh, nx);

    // ---- CSR build ----
    zero_int<<<(N + 255) / 256, 256, 0, stream>>>(deg, N);
    hist_kernel<<<(E + 255) / 256, 256, 0, stream>>>(dst, deg, E);
    scan1<<<nb, 1024, 0, stream>>>(deg, offs, bsums, N);
    scan2<<<1, 1024, 0, stream>>>(bsums, boffs, offs, nb, N);
    scan3<<<nb, 1024, 0, stream>>>(offs, cur, boffs, N);
    scatter_kernel<<<(E + 255) / 256, 256, 0, stream>>>(src, dst, cur, sorted, E);

    dim3 gg((N + 127) / 128, 2);
    int aggblocks = (N + 3) / 4;
    sort_csr<<<aggblocks, 256, 0, stream>>>(offs, sorted, N);

    // ---- layer 1 ----
    gemm_mfma<<<gg, 256, 0, stream>>>(xh, w1h, hp, N);
    scompute<4><<<aggblocks, 256, 0, stream>>>(hp, a1s, a1d, ssrc, sdst, N);
    aggregate4<4, true, true><<<aggblocks, 256, 0, stream>>>(hp, ssrc, sdst, offs, sorted,
                                                             nullptr, hh, N);

    // ---- layer 2 ----
    gemm_mfma<<<gg, 256, 0, stream>>>(hh, w2h, hp, N);
    scompute<1><<<aggblocks, 256, 0, stream>>>(hp, a2s, a2d, ssrc, sdst, N);
    aggregate4<1, false, false><<<aggblocks, 256, 0, stream>>>(hp, ssrc, sdst, offs, sorted,
                                                               out, nullptr, N);
}